// Round 6
// baseline (79.299 us; speedup 1.0000x reference)
//
#include <hip/hip_runtime.h>
#include <cstdint>

#define CCLS 10
#define DDIM 256
#define NCHUNK 256          // chunks per view -> 512 blocks total (2/CU)
#define UNR 8               // rows unrolled per wave in main loop
#define RPC_MAX 800         // max rows per chunk the LDS mask table holds
#define CD4 (CCLS * DDIM / 4)   // 640 f32x4 output columns

typedef float f32x4 __attribute__((ext_vector_type(4)));

__device__ inline f32x4 ntload4(const f32x4* p) {
    return __builtin_nontemporal_load(p);
}
__device__ inline uint32_t rfl(uint32_t x) {
    return (uint32_t)__builtin_amdgcn_readfirstlane((int)x);
}

// ---------------------------------------------------------------------------
// Fused main kernel. Block = (chunk, v). 256 threads = 4 waves; wave w owns
// rows n0+w, n0+w+4, ...  Whole wave shares a row -> mask is wave-uniform.
// Block start: stage this chunk's y-slice -> 10-bit keep masks in LDS (once),
// with the first UNR x-loads already in flight to hide the staging latency.
// Hot loop: 1-deep software pipeline, UNR rows (8 KB/wave) in flight.
// EPI==0: store per-block partials TRANSPOSED to ws: part[v][j4][chunk]
//         (f32x4 granularity) so the reduce kernel reads coalesced rows.
// EPI==1: atomicAdd into pre-zeroed out (fallback when ws is too small).
template <int EPI>
__global__ __launch_bounds__(256, 2) void masked_sum_kernel(
    const float* __restrict__ x,      // [V, N, D]
    const int* __restrict__ y,        // [N, C]
    float* __restrict__ dst,          // EPI==0: partials [V, CD4, nchunk] f32x4; else out
    int N, int rows_per_chunk, int nchunk)
{
    const int v = blockIdx.y;
    const int chunk = blockIdx.x;
    const int n0 = chunk * rows_per_chunk;
    const int n1 = min(n0 + rows_per_chunk, N);
    const int nr = n1 - n0;
    const int row = threadIdx.x >> 6;   // wave id 0..3
    const int d4  = threadIdx.x & 63;   // float4 index within row

    __shared__ uint32_t smask[RPC_MAX];           // 3.2 KB
    __shared__ f32x4 lred[4][CCLS][DDIM / 4];     // 40 KB

    const f32x4* __restrict__ xb =
        reinterpret_cast<const f32x4*>(x + (size_t)v * N * DDIM);

    f32x4 acc[CCLS];
    #pragma unroll
    for (int c = 0; c < CCLS; ++c) acc[c] = (f32x4){0.f, 0.f, 0.f, 0.f};

    // --- issue iteration-0 x loads (latency overlaps the mask staging) ---
    int n = n0 + row;
    bool have = (n + 4 * (UNR - 1) < n1);
    f32x4 xv[UNR];
    if (have) {
        #pragma unroll
        for (int u = 0; u < UNR; ++u)
            xv[u] = ntload4(xb + (size_t)(n + 4 * u) * (DDIM / 4) + d4);
    }

    // --- stage masks: thread t handles rows t, t+256, ... ---
    for (int r = threadIdx.x; r < nr; r += 256) {
        const int* __restrict__ yr = y + (size_t)(n0 + r) * CCLS;
        uint32_t m = 0;
        #pragma unroll
        for (int c = 0; c < CCLS; ++c)
            m |= (yr[c] == 0 ? 1u : 0u) << c;
        smask[r] = m;
    }
    __syncthreads();

    // --- hot loop: 1-deep pipeline, UNR rows per wave per iteration ---
    while (have) {
        const int nn = n + 4 * UNR;
        const bool hnext = (nn + 4 * (UNR - 1) < n1);
        f32x4 xn[UNR];
        if (hnext) {
            #pragma unroll
            for (int u = 0; u < UNR; ++u)
                xn[u] = ntload4(xb + (size_t)(nn + 4 * u) * (DDIM / 4) + d4);
        }
        #pragma unroll
        for (int u = 0; u < UNR; ++u) {
            const uint32_t m = rfl(smask[n - n0 + 4 * u]);
            #pragma unroll
            for (int c = 0; c < CCLS; ++c)
                acc[c] += (((m >> c) & 1u) ? 1.0f : 0.0f) * xv[u];
        }
        #pragma unroll
        for (int u = 0; u < UNR; ++u) xv[u] = xn[u];
        n = nn; have = hnext;
    }
    // remainder rows
    for (; n < n1; n += 4) {
        f32x4 x0 = ntload4(xb + (size_t)n * (DDIM / 4) + d4);
        const uint32_t m = rfl(smask[n - n0]);
        #pragma unroll
        for (int c = 0; c < CCLS; ++c)
            acc[c] += (((m >> c) & 1u) ? 1.0f : 0.0f) * x0;
    }

    // --- cross-wave reduction: plain writes, one sync, plain reads ---
    #pragma unroll
    for (int c = 0; c < CCLS; ++c)
        lred[row][c][d4] = acc[c];
    __syncthreads();

    const f32x4* __restrict__ lf = &lred[0][0][0];        // [4][640]
    if (EPI == 0) {
        // transposed store: part[v][j4][chunk], 16 B per store, stride 4*nchunk B
        f32x4* __restrict__ dstv = reinterpret_cast<f32x4*>(dst);
        for (int j = threadIdx.x; j < CD4; j += 256) {
            f32x4 s = (lf[j] + lf[640 + j]) + (lf[1280 + j] + lf[1920 + j]);
            dstv[((size_t)v * CD4 + j) * nchunk + chunk] = s;
        }
    } else {
        float* __restrict__ outv = dst + (size_t)v * (CCLS * DDIM);
        for (int j = threadIdx.x; j < CD4; j += 256) {
            f32x4 s = (lf[j] + lf[640 + j]) + (lf[1280 + j] + lf[1920 + j]);
            atomicAdd(&outv[4 * j + 0], s.x);
            atomicAdd(&outv[4 * j + 1], s.y);
            atomicAdd(&outv[4 * j + 2], s.z);
            atomicAdd(&outv[4 * j + 3], s.w);
        }
    }
}

// ---------------------------------------------------------------------------
// Final reduction over the transposed partials. Grid (CD4/4 = 160, V),
// 256 threads = 4 waves. Wave w owns f32x4-row r = bx*4 + w: a contiguous
// run of nchunk f32x4 (4 KB at nchunk=256). Lane l sums chunks l, l+64, ...
// (fully coalesced 1 KB wave-loads), then shfl_xor collapses 64 lanes;
// lane 0 writes the final f32x4. Deterministic, no atomics, no pre-zero.
__global__ __launch_bounds__(256) void reduce_parts_kernel(
    const float* __restrict__ part, float* __restrict__ out, int nchunk)
{
    const int v = blockIdx.y;
    const int w = threadIdx.x >> 6, l = threadIdx.x & 63;
    const int r = blockIdx.x * 4 + w;             // f32x4 row in [0, CD4)
    const f32x4* __restrict__ b =
        reinterpret_cast<const f32x4*>(part) + ((size_t)v * CD4 + r) * nchunk;

    f32x4 s = (f32x4){0.f, 0.f, 0.f, 0.f};
    #pragma unroll 4
    for (int c = l; c < nchunk; c += 64)
        s += b[c];

    #pragma unroll
    for (int off = 1; off < 64; off <<= 1) {
        s.x += __shfl_xor(s.x, off);
        s.y += __shfl_xor(s.y, off);
        s.z += __shfl_xor(s.z, off);
        s.w += __shfl_xor(s.w, off);
    }
    if (l == 0)
        reinterpret_cast<f32x4*>(out)[(size_t)v * CD4 + r] = s;
}

// ---------------------------------------------------------------------------
extern "C" void kernel_launch(void* const* d_in, const int* in_sizes, int n_in,
                              void* d_out, int out_size, void* d_ws, size_t ws_size,
                              hipStream_t stream) {
    const int*   y = (const int*)d_in[0];         // [N, 10]
    const float* x = (const float*)d_in[1];       // [V, N, 256]
    float* out = (float*)d_out;                   // [V, 2560]

    const int N = in_sizes[0] / CCLS;             // 200000
    const int V = in_sizes[1] / (N * DDIM);       // 2

    // Ensure rows_per_chunk <= RPC_MAX (LDS mask table size).
    int nchunk = NCHUNK;
    while ((N + nchunk - 1) / nchunk > RPC_MAX) nchunk += 64;
    const int rpc = (N + nchunk - 1) / nchunk;

    const size_t part_bytes = (size_t)V * CD4 * nchunk * sizeof(f32x4);
    dim3 grid(nchunk, V);

    if (ws_size >= part_bytes) {
        float* part = (float*)d_ws;
        masked_sum_kernel<0><<<grid, 256, 0, stream>>>(x, y, part, N, rpc, nchunk);
        reduce_parts_kernel<<<dim3(CD4 / 4, V), 256, 0, stream>>>(part, out, nchunk);
    } else {
        hipMemsetAsync(d_out, 0, (size_t)out_size * sizeof(float), stream);
        masked_sum_kernel<1><<<grid, 256, 0, stream>>>(x, y, out, N, rpc, nchunk);
    }
}

// Round 8
// 75.213 us; speedup vs baseline: 1.0543x; 1.0543x over previous
//
#include <hip/hip_runtime.h>
#include <cstdint>

#define CCLS 10
#define DDIM 256
#define NCHUNK 256          // chunks per view -> 512 blocks total (2/CU)
#define UNR 8               // rows unrolled per wave in main loop
#define RPC_MAX 800         // max rows per chunk the LDS mask table holds
#define CD4 (CCLS * DDIM / 4)   // 640 f32x4 output columns

typedef float f32x4 __attribute__((ext_vector_type(4)));

__device__ inline f32x4 ntload4(const f32x4* p) {
    return __builtin_nontemporal_load(p);
}
__device__ inline uint32_t rfl(uint32_t x) {
    return (uint32_t)__builtin_amdgcn_readfirstlane((int)x);
}

// ---------------------------------------------------------------------------
// Fused main kernel. Block = (chunk, v). 256 threads = 4 waves; wave w owns
// rows n0+w, n0+w+4, ...  Whole wave shares a row -> mask is wave-uniform.
// Block start: stage this chunk's y-slice -> 10-bit keep masks in LDS (once),
// with the first UNR x-loads already in flight to hide the staging latency.
// Hot loop: 1-deep software pipeline, UNR rows (8 KB/wave) in flight.
// EPI==0: plain coalesced store of per-block partials [v][chunk][j] to ws.
//         (NOT transposed: round-6 measured that a [v][j][chunk] layout makes
//          chunks c..c+3 share a 64B line across blocks on different XCDs ->
//          cross-XCD write bounce, +4.4 us. Keep stores block-local/coalesced.)
// EPI==1: atomicAdd into pre-zeroed out (fallback when ws is too small).
template <int EPI>
__global__ __launch_bounds__(256, 2) void masked_sum_kernel(
    const float* __restrict__ x,      // [V, N, D]
    const int* __restrict__ y,        // [N, C]
    float* __restrict__ dst,          // EPI==0: partials [V, nchunk, C*D]; else out
    int N, int rows_per_chunk, int nchunk)
{
    const int v = blockIdx.y;
    const int chunk = blockIdx.x;
    const int n0 = chunk * rows_per_chunk;
    const int n1 = min(n0 + rows_per_chunk, N);
    const int nr = n1 - n0;
    const int row = threadIdx.x >> 6;   // wave id 0..3
    const int d4  = threadIdx.x & 63;   // float4 index within row

    __shared__ uint32_t smask[RPC_MAX];           // 3.2 KB
    __shared__ f32x4 lred[4][CCLS][DDIM / 4];     // 40 KB

    const f32x4* __restrict__ xb =
        reinterpret_cast<const f32x4*>(x + (size_t)v * N * DDIM);

    f32x4 acc[CCLS];
    #pragma unroll
    for (int c = 0; c < CCLS; ++c) acc[c] = (f32x4){0.f, 0.f, 0.f, 0.f};

    // --- issue iteration-0 x loads (latency overlaps the mask staging) ---
    int n = n0 + row;
    bool have = (n + 4 * (UNR - 1) < n1);
    f32x4 xv[UNR];
    if (have) {
        #pragma unroll
        for (int u = 0; u < UNR; ++u)
            xv[u] = ntload4(xb + (size_t)(n + 4 * u) * (DDIM / 4) + d4);
    }

    // --- stage masks: thread t handles rows t, t+256, ... ---
    for (int r = threadIdx.x; r < nr; r += 256) {
        const int* __restrict__ yr = y + (size_t)(n0 + r) * CCLS;
        uint32_t m = 0;
        #pragma unroll
        for (int c = 0; c < CCLS; ++c)
            m |= (yr[c] == 0 ? 1u : 0u) << c;
        smask[r] = m;
    }
    __syncthreads();

    // --- hot loop: 1-deep pipeline, UNR rows per wave per iteration ---
    while (have) {
        const int nn = n + 4 * UNR;
        const bool hnext = (nn + 4 * (UNR - 1) < n1);
        f32x4 xn[UNR];
        if (hnext) {
            #pragma unroll
            for (int u = 0; u < UNR; ++u)
                xn[u] = ntload4(xb + (size_t)(nn + 4 * u) * (DDIM / 4) + d4);
        }
        #pragma unroll
        for (int u = 0; u < UNR; ++u) {
            const uint32_t m = rfl(smask[n - n0 + 4 * u]);
            #pragma unroll
            for (int c = 0; c < CCLS; ++c)
                acc[c] += (((m >> c) & 1u) ? 1.0f : 0.0f) * xv[u];
        }
        #pragma unroll
        for (int u = 0; u < UNR; ++u) xv[u] = xn[u];
        n = nn; have = hnext;
    }
    // remainder rows
    for (; n < n1; n += 4) {
        f32x4 x0 = ntload4(xb + (size_t)n * (DDIM / 4) + d4);
        const uint32_t m = rfl(smask[n - n0]);
        #pragma unroll
        for (int c = 0; c < CCLS; ++c)
            acc[c] += (((m >> c) & 1u) ? 1.0f : 0.0f) * x0;
    }

    // --- cross-wave reduction: plain writes, one sync, plain reads ---
    #pragma unroll
    for (int c = 0; c < CCLS; ++c)
        lred[row][c][d4] = acc[c];
    __syncthreads();

    const f32x4* __restrict__ lf = &lred[0][0][0];        // [4][640]
    if (EPI == 0) {
        f32x4* __restrict__ dstv = reinterpret_cast<f32x4*>(
            dst + ((size_t)v * nchunk + chunk) * (CCLS * DDIM));
        for (int j = threadIdx.x; j < CD4; j += 256) {
            f32x4 s = (lf[j] + lf[640 + j]) + (lf[1280 + j] + lf[1920 + j]);
            dstv[j] = s;
        }
    } else {
        float* __restrict__ outv = dst + (size_t)v * (CCLS * DDIM);
        for (int j = threadIdx.x; j < CD4; j += 256) {
            f32x4 s = (lf[j] + lf[640 + j]) + (lf[1280 + j] + lf[1920 + j]);
            atomicAdd(&outv[4 * j + 0], s.x);
            atomicAdd(&outv[4 * j + 1], s.y);
            atomicAdd(&outv[4 * j + 2], s.z);
            atomicAdd(&outv[4 * j + 3], s.w);
        }
    }
}

// ---------------------------------------------------------------------------
// Deterministic final reduction, no atomics, no pre-zero needed.
// Grid (CD4/4 = 160, V), 256 threads = 4 waves.  Block owns 4 f32x4 output
// columns.  Wave w covers chunks [w*cpw, (w+1)*cpw); lane l: col = bx*4 +
// (l&3), slot = l>>2; shfl_xor collapses the 16 slots; LDS collapses 4 waves.
__global__ __launch_bounds__(256) void reduce_parts_kernel(
    const float* __restrict__ part, float* __restrict__ out, int nchunk)
{
    const int v = blockIdx.y;
    const int w = threadIdx.x >> 6, l = threadIdx.x & 63;
    const int colbase = blockIdx.x * 4;
    const int col = colbase + (l & 3);            // f32x4 index in [0, 640)
    const int slot = l >> 2;                      // 0..15
    const int cpw = nchunk / 4;                   // chunks per wave
    const f32x4* __restrict__ b =
        reinterpret_cast<const f32x4*>(part) + (size_t)v * nchunk * CD4;

    f32x4 s = (f32x4){0.f, 0.f, 0.f, 0.f};
    #pragma unroll 4
    for (int ch = w * cpw + slot; ch < (w + 1) * cpw; ch += 16)
        s += b[(size_t)ch * CD4 + col];

    #pragma unroll
    for (int off = 4; off < 64; off <<= 1) {
        s.x += __shfl_xor(s.x, off);
        s.y += __shfl_xor(s.y, off);
        s.z += __shfl_xor(s.z, off);
        s.w += __shfl_xor(s.w, off);
    }

    __shared__ f32x4 lred[4][4];
    if (l < 4) lred[w][l] = s;
    __syncthreads();
    if (threadIdx.x < 4) {
        f32x4 t = (lred[0][threadIdx.x] + lred[1][threadIdx.x]) +
                  (lred[2][threadIdx.x] + lred[3][threadIdx.x]);
        reinterpret_cast<f32x4*>(out)[(size_t)v * CD4 + colbase + threadIdx.x] = t;
    }
}

// ---------------------------------------------------------------------------
extern "C" void kernel_launch(void* const* d_in, const int* in_sizes, int n_in,
                              void* d_out, int out_size, void* d_ws, size_t ws_size,
                              hipStream_t stream) {
    const int*   y = (const int*)d_in[0];         // [N, 10]
    const float* x = (const float*)d_in[1];       // [V, N, 256]
    float* out = (float*)d_out;                   // [V, 2560]

    const int N = in_sizes[0] / CCLS;             // 200000
    const int V = in_sizes[1] / (N * DDIM);       // 2

    // Ensure rows_per_chunk <= RPC_MAX (LDS mask table size).
    int nchunk = NCHUNK;
    while ((N + nchunk - 1) / nchunk > RPC_MAX) nchunk += 64;
    const int rpc = (N + nchunk - 1) / nchunk;

    const size_t part_bytes = (size_t)V * nchunk * CCLS * DDIM * sizeof(float);
    dim3 grid(nchunk, V);

    if (ws_size >= part_bytes) {
        float* part = (float*)d_ws;
        masked_sum_kernel<0><<<grid, 256, 0, stream>>>(x, y, part, N, rpc, nchunk);
        // 4 f32x4 columns per block -> CD4/4 = 160 blocks (round-7 bug: /16
        // launched only 40 blocks and left 3/4 of out unwritten).
        reduce_parts_kernel<<<dim3(CD4 / 4, V), 256, 0, stream>>>(part, out, nchunk);
    } else {
        hipMemsetAsync(d_out, 0, (size_t)out_size * sizeof(float), stream);
        masked_sum_kernel<1><<<grid, 256, 0, stream>>>(x, y, out, N, rpc, nchunk);
    }
}